// Round 6
// baseline (517.287 us; speedup 1.0000x reference)
//
#include <hip/hip_runtime.h>
#include <cstddef>

// DynamicNetwork via split-bf16 MFMA (hi/lo, 3 MFMA per product).
// R8: algebraic fusion — nodes 2..5 never materialized.
// R9: prepvec re-parallelized. R10/R11 (reverted). R12/R13: BM64 grid-512 — no
//     change vs R9 (51us/GEMM): grid gave only 2 blocks/CU and __syncthreads'
//     vmcnt(0) drain killed the depth-2 prefetch every step.
// R14: attack both: (a) raw s_barrier + lgkmcnt(0)-only (no vmcnt drain ->
//     prefetch really stays 2 steps in flight; dbuf+1-barrier/step is race-free:
//     a thread reaches the k+2 overwrite of buf0 only after barrier k+1, which
//     requires all threads' lgkmcnt(0) => their buf0 reads completed);
//     (b) BM32 x BN128, grid 1024 = 4 blocks/CU (LDS 30KB, 4 waves, 1 acc,
//     3 MFMA/step) so barrier stalls overlap across blocks.

typedef short short8 __attribute__((ext_vector_type(8)));
typedef float floatx16 __attribute__((ext_vector_type(16)));

#define EMB_BLOCKS 832
#define SN0 224   // node0 k-stride (208 used)
#define SN1 448   // node1 k-stride (416 used)
#define SH  416   // hidden k-stride (400 used)

__device__ __forceinline__ unsigned short f2bf(float f) {
    unsigned int u = __float_as_uint(f);
    u += 0x7fffu + ((u >> 16) & 1u);
    return (unsigned short)(u >> 16);
}
__device__ __forceinline__ float bf2f(unsigned short h) {
    return __uint_as_float((unsigned int)h << 16);
}
__device__ __forceinline__ void split2(float v, unsigned short& h, unsigned short& l) {
    h = f2bf(v);
    l = f2bf(v - bf2f(h));
}

// ---------------- prep1: column sums (39 blocks) + alpha scalars ----------------
__global__ __launch_bounds__(256) void prep1_kernel(
    const float* __restrict__ Pd, const float* __restrict__ Ps, const float* __restrict__ Pb,
    const float* __restrict__ a0, const float* __restrict__ a1,
    const float* __restrict__ a2, const float* __restrict__ a3,
    float* __restrict__ scal,
    float* __restrict__ csd, float* __restrict__ css, float* __restrict__ csb)
{
    int t = threadIdx.x;
    int y = blockIdx.y;
    int c = t & 31, rg = t >> 5;
    int col = blockIdx.x * 32 + c;
    const float* src = (y==0) ? Pd : (y==1) ? Ps : Pb;
    int K = (y==0) ? 208 : (y==1) ? 416 : 400;
    float* out = (y==0) ? csd : (y==1) ? css : csb;
    float s = 0.f;
    if (col < 400)
        for (int k = rg; k < K; k += 8) s += src[(size_t)k*400 + col];
    __shared__ float red[8][32];
    red[rg][c] = s;
    __syncthreads();
    if (rg == 0 && col < 400) {
        float tot = 0.f;
        #pragma unroll
        for (int r = 0; r < 8; ++r) tot += red[r][c];
        out[col] = tot;
    }
    if (blockIdx.x == 0 && y == 0 && t < 4) {
        int i = t;
        const float* a = (i==0) ? a0 : (i==1) ? a1 : (i==2) ? a2 : a3;
        int np = 2 + i;
        float sum1 = 0.f, sum2 = 0.f, sumc = 0.f;
        for (int j = 0; j < np; ++j) { sum1 += a[j]; sum2 += a[np+j]; }
        for (int j = 0; j < 4; ++j) sumc += a[2*np+j];
        int i1 = (i==0) ? 0 : 1;
        int i2 = i + 1;
        int kk = i;
        float s1 = a[i1],      c1 = sum1 - s1;
        float s2 = a[np+i2],   c2 = sum2 - s2;
        float sk = a[2*np+kk], ck = sumc - sk;
        float* sl = scal + i*8;
        if (i == 0) { sl[0]=s1; sl[1]=c1; sl[2]=s2; sl[3]=c2; }
        else        { sl[0]=s2; sl[1]=c2; sl[2]=s1; sl[3]=c1; }
        sl[4] = sk; sl[5] = ck;
    }
}

// ---------------- prep2: Ps/Pd regions of weight planes [2][512][Kw] ----------------
__global__ __launch_bounds__(256) void prep2_kernel(
    const float* __restrict__ Pd, const float* __restrict__ Ps,
    const float* __restrict__ Pb,
    const float* __restrict__ scal,
    unsigned short* __restrict__ w0, unsigned short* __restrict__ w1,
    unsigned short* __restrict__ w2, unsigned short* __restrict__ w3)
{
    int z = blockIdx.z;
    int Kp = (z==0) ? 624 : 816;
    int KA = (z==0) ? 208 : 400;
    int Kw = (z==0) ? 640 : 832;
    const float* sA = (z==0) ? Pd : Pb;
    const float* sB = Ps;
    float sc1 = scal[z*8+0];
    float sc2 = scal[z*8+2];
    unsigned short* dst = (z==0) ? w0 : (z==1) ? w1 : (z==2) ? w2 : w3;

    int ktiles = (Kp + 63) >> 6;
    if ((int)blockIdx.y >= ktiles) return;
    int k0 = blockIdx.y * 64, n0 = blockIdx.x * 64;
    __shared__ float T[64][65];
    int t = threadIdx.x;
    {
        int kr = t >> 2, c0 = (t & 3) * 16;
        int gk = k0 + kr;
        bool kok = gk < Kp;
        const float* src; int srow; float sc;
        if (gk < KA) { src = sA; srow = gk; sc = sc1; }
        else         { src = sB; srow = gk - KA; sc = sc2; }
        for (int j = 0; j < 16; j += 4) {
            int n = n0 + c0 + j;
            float4 v = make_float4(0.f,0.f,0.f,0.f);
            if (kok && n < 400) v = *(const float4*)&src[(size_t)srow*400 + n];
            T[kr][c0+j+0] = v.x * sc;
            T[kr][c0+j+1] = v.y * sc;
            T[kr][c0+j+2] = v.z * sc;
            T[kr][c0+j+3] = v.w * sc;
        }
    }
    __syncthreads();
    {
        int nr = t >> 2, kc0 = (t & 3) * 16;
        int gn = n0 + nr;
        int gk0 = k0 + kc0;
        if (gk0 >= Kp) return;
        if (z > 0 && gk0 < 400) return;   // M-region written by prepM
        unsigned short hb[16], lb[16];
        for (int j = 0; j < 16; ++j) {
            float v = (gn < 400) ? T[kc0+j][nr] : 0.f;
            split2(v, hb[j], lb[j]);
        }
        unsigned short* dh = dst + (size_t)gn*Kw + gk0;
        unsigned short* dl = dst + (size_t)512*Kw + (size_t)gn*Kw + gk0;
        *(uint4*)&dh[0] = *(uint4*)&hb[0]; *(uint4*)&dh[8] = *(uint4*)&hb[8];
        *(uint4*)&dl[0] = *(uint4*)&lb[0]; *(uint4*)&dl[8] = *(uint4*)&lb[8];
    }
}

// ---------------- prepM: M_g = s2_g * sk_{g-1} * (Wc_{g-1} @ Pb), g = z+1 ----------------
__global__ __launch_bounds__(256) void prepM_kernel(
    const float* __restrict__ Wc, const float* __restrict__ Pb,
    const float* __restrict__ scal,
    unsigned short* __restrict__ w1, unsigned short* __restrict__ w2,
    unsigned short* __restrict__ w3)
{
    int z = blockIdx.z;                   // 0..2 -> GEMM g = z+1
    unsigned short* dst = (z==0) ? w1 : (z==1) ? w2 : w3;
    const float* A = Wc + (size_t)z*5*160000;   // Wc[z, kk=z] : [400k][400j]
    float scale = scal[(z+1)*8+0] * scal[z*8+4];
    const int Kw = 832;

    __shared__ float As[16][68];   // [j][k]
    __shared__ float Ws[16][68];   // [j][n]
    int t = threadIdx.x;
    int tx = t & 15, ty = t >> 4;
    int bk = blockIdx.y * 64;
    int bn = blockIdx.x * 64;
    int arow = t >> 2;
    int aj4  = (t & 3) << 2;
    int wrow = t >> 4;
    int wc4  = (t & 15) << 2;
    float acc[4][4] = {};
    for (int j0 = 0; j0 < 400; j0 += 16) {
        float4 av = make_float4(0.f,0.f,0.f,0.f);
        if (bk + arow < 400) av = *(const float4*)&A[(size_t)(bk+arow)*400 + j0 + aj4];
        float4 wv = make_float4(0.f,0.f,0.f,0.f);
        if (bn + wc4 < 400) wv = *(const float4*)&Pb[(size_t)(j0+wrow)*400 + bn + wc4];
        __syncthreads();
        As[aj4+0][arow] = av.x;
        As[aj4+1][arow] = av.y;
        As[aj4+2][arow] = av.z;
        As[aj4+3][arow] = av.w;
        *(float4*)&Ws[wrow][wc4] = wv;
        __syncthreads();
        #pragma unroll
        for (int jj = 0; jj < 16; ++jj) {
            float4 a4 = *(const float4*)&As[jj][ty<<2];
            float4 b4 = *(const float4*)&Ws[jj][tx<<2];
            acc[0][0] += a4.x*b4.x; acc[0][1] += a4.x*b4.y; acc[0][2] += a4.x*b4.z; acc[0][3] += a4.x*b4.w;
            acc[1][0] += a4.y*b4.x; acc[1][1] += a4.y*b4.y; acc[1][2] += a4.y*b4.z; acc[1][3] += a4.y*b4.w;
            acc[2][0] += a4.z*b4.x; acc[2][1] += a4.z*b4.y; acc[2][2] += a4.z*b4.z; acc[2][3] += a4.z*b4.w;
            acc[3][0] += a4.w*b4.x; acc[3][1] += a4.w*b4.y; acc[3][2] += a4.w*b4.z; acc[3][3] += a4.w*b4.w;
        }
    }
    int gk0 = bk + (ty << 2);
    int gn0 = bn + (tx << 2);
    #pragma unroll
    for (int ik = 0; ik < 4; ++ik) {
        int gk = gk0 + ik;
        if (gk >= 400) break;
        #pragma unroll
        for (int in = 0; in < 4; ++in) {
            int gn = gn0 + in;
            float v = (gn < 400) ? acc[ik][in] * scale : 0.f;
            unsigned short h16, l16; split2(v, h16, l16);
            dst[(size_t)gn*Kw + gk] = h16;
            dst[(size_t)512*Kw + (size_t)gn*Kw + gk] = l16;
        }
    }
}

// ---------------- prepvec: C_i, gv_i, scalar consts (56 blocks) ----------------
__global__ __launch_bounds__(256) void prepvec_kernel(
    const float* __restrict__ scal,
    const float* __restrict__ csd, const float* __restrict__ css, const float* __restrict__ csb,
    const float* __restrict__ Wc, const float* __restrict__ bc,
    const float* __restrict__ clf_w, const float* __restrict__ Pb,
    float* __restrict__ cv, float* __restrict__ gv, float* __restrict__ scl2)
{
    int i = blockIdx.y;
    int tid = threadIdx.x;
    int tbase = blockIdx.x * 32;
    const float* cw = clf_w + i*400;
    float ski = scal[i*8+4], cki = scal[i*8+5];
    const float* A = Wc + (size_t)i*5*160000;

    int wv = tid >> 6, lane = tid & 63;
    #pragma unroll
    for (int q = 0; q < 8; ++q) {
        int t = tbase + wv*8 + q;
        float s = 0.f;
        if (t < 400) {
            const float* wr = A + (size_t)t*400;
            for (int j = lane; j < 400; j += 64) s += wr[j]*cw[j];
            #pragma unroll
            for (int o = 32; o > 0; o >>= 1) s += __shfl_xor(s, o);
        }
        if (lane == 0) gv[i*448 + t] = (t < 400) ? ski * s : 0.f;
    }

    __shared__ float bpred[8][32];
    int t = tbase + (tid & 31);
    int jc = tid >> 5;
    float bp_part = 0.f;
    if (i > 0 && t < 400) {
        const float* bcp = bc + (size_t)(i-1)*5*400;
        for (int j = jc*50; j < jc*50 + 50; ++j)
            bp_part += bcp[j] * Pb[(size_t)j*400 + t];
    }
    bpred[jc][tid & 31] = bp_part;
    __syncthreads();
    if (tid < 32) {
        float bp = 0.f;
        #pragma unroll
        for (int r = 0; r < 8; ++r) bp += bpred[r][tid];
        float c = 0.f;
        if (t < 400) {
            if (i == 0) {
                c = scal[1]*csd[t] + scal[3]*css[t];
            } else {
                float s2 = scal[i*8+0], c2 = scal[i*8+1];
                float c1 = scal[i*8+3];
                float skp = scal[(i-1)*8+4], ckp = scal[(i-1)*8+5];
                c = c1*css[t] + (c2 + s2*ckp)*csb[t] + s2*skp*bp;
            }
        }
        cv[i*448 + t] = c;
    }

    if (blockIdx.x == 0) {
        const float* bci = bc + (size_t)i*5*400;
        float sc = 0.f;
        for (int j = tid; j < 400; j += 256) sc += (ski*bci[j] + cki)*cw[j];
        #pragma unroll
        for (int o = 32; o > 0; o >>= 1) sc += __shfl_down(sc, o);
        __shared__ float red[4];
        int wv2 = tid >> 6, ln = tid & 63;
        if (ln == 0) red[wv2] = sc;
        __syncthreads();
        if (tid == 0) scl2[i] = red[0]+red[1]+red[2]+red[3];
    }
}

// ---------------- embed: node0/node1 bf16 hi/lo planes (padded strides) ----------------
__global__ __launch_bounds__(256) void embed_kernel(
    const float* __restrict__ rd, const int* __restrict__ rs,
    const float* __restrict__ emb,
    unsigned short* __restrict__ n0h, unsigned short* __restrict__ n0l,
    unsigned short* __restrict__ n1h, unsigned short* __restrict__ n1l,
    float* __restrict__ partial)
{
    int tid0 = blockIdx.x*256 + threadIdx.x;
    int nth = gridDim.x*256;
    float ssq = 0.f, dsq = 0.f;
    for (int it = tid0; it < 8192*26; it += nth) {
        int b = it / 26, s = it - b*26;
        int row = 13 + 50000*s + rs[b*26 + s];
        const float* e = emb + (size_t)row*16;
        float4 e0 = *(const float4*)&e[0], e1 = *(const float4*)&e[4];
        float4 e2 = *(const float4*)&e[8], e3 = *(const float4*)&e[12];
        float vv[16] = {e0.x,e0.y,e0.z,e0.w, e1.x,e1.y,e1.z,e1.w,
                        e2.x,e2.y,e2.z,e2.w, e3.x,e3.y,e3.z,e3.w};
        unsigned short hb[16], lb[16];
        for (int j = 0; j < 16; ++j) { ssq += vv[j]*vv[j]; split2(vv[j], hb[j], lb[j]); }
        size_t off = (size_t)b*SN1 + s*16;
        *(uint4*)&n1h[off] = *(uint4*)&hb[0]; *(uint4*)&n1h[off+8] = *(uint4*)&hb[8];
        *(uint4*)&n1l[off] = *(uint4*)&lb[0]; *(uint4*)&n1l[off+8] = *(uint4*)&lb[8];
    }
    for (int it = tid0; it < 8192*13; it += nth) {
        int b = it / 13, f = it - b*13;
        float sc = rd[b*13 + f];
        const float* e = emb + (size_t)f*16;
        float4 e0 = *(const float4*)&e[0], e1 = *(const float4*)&e[4];
        float4 e2 = *(const float4*)&e[8], e3 = *(const float4*)&e[12];
        float vv[16] = {e0.x,e0.y,e0.z,e0.w, e1.x,e1.y,e1.z,e1.w,
                        e2.x,e2.y,e2.z,e2.w, e3.x,e3.y,e3.z,e3.w};
        unsigned short hb[16], lb[16];
        for (int j = 0; j < 16; ++j) { float v = vv[j]*sc; dsq += v*v; split2(v, hb[j], lb[j]); }
        size_t off = (size_t)b*SN0 + f*16;
        *(uint4*)&n0h[off] = *(uint4*)&hb[0]; *(uint4*)&n0h[off+8] = *(uint4*)&hb[8];
        *(uint4*)&n0l[off] = *(uint4*)&lb[0]; *(uint4*)&n0l[off+8] = *(uint4*)&lb[8];
    }
    for (int o = 32; o > 0; o >>= 1) { ssq += __shfl_down(ssq, o); dsq += __shfl_down(dsq, o); }
    __shared__ float red[8];
    int wave = threadIdx.x >> 6, lane = threadIdx.x & 63;
    if (lane == 0) { red[wave] = dsq; red[4+wave] = ssq; }
    __syncthreads();
    if (threadIdx.x == 0) {
        partial[blockIdx.x*2]   = red[0]+red[1]+red[2]+red[3];
        partial[blockIdx.x*2+1] = red[4]+red[5]+red[6]+red[7];
    }
}

// blocks 0..31: out[b] = clf_b + sum_i scl2[i]; block 32: regs
__global__ __launch_bounds__(256) void finalize_kernel(
    const float* __restrict__ clf_b, const float* __restrict__ partial,
    const float* __restrict__ scl2, float* __restrict__ out)
{
    if (blockIdx.x < 32) {
        float base = clf_b[0] + scl2[0] + scl2[1] + scl2[2] + scl2[3];
        out[blockIdx.x*256 + threadIdx.x] = base;
        return;
    }
    float d = 0.f, s = 0.f;
    for (int i = threadIdx.x; i < EMB_BLOCKS; i += 256) { d += partial[2*i]; s += partial[2*i+1]; }
    for (int o = 32; o > 0; o >>= 1) { d += __shfl_down(d, o); s += __shfl_down(s, o); }
    __shared__ float red[8];
    int wave = threadIdx.x >> 6, lane = threadIdx.x & 63;
    if (lane == 0) { red[wave] = d; red[4+wave] = s; }
    __syncthreads();
    if (threadIdx.x == 0) {
        float dd = red[0]+red[1]+red[2]+red[3];
        float ss = red[4]+red[5]+red[6]+red[7];
        out[8192] = 1e-5f * (sqrtf(dd) + sqrtf(ss));
    }
}

// ---------------- R14 MFMA GEMM: BM32 x BN128, 4 waves, raw barrier ----------------
// Grid 1024 = 256 mt x 4 nt (XCD swizzle) -> 4 blocks/CU. 4 waves; wave W owns
// 32 cols (nw=W), full K, single acc. LDS 30 KB: per buf (7680 sh):
//   A [2pl][32][24] @ 0 (1536 sh) | B [2pl][128][24] @ 1536 (6144 sh).
// K-loop barrier = lgkmcnt(0) + raw s_barrier (NO vmcnt drain): depth-2 global
// prefetch stays in flight across barriers. Race-free (see header note).
__global__ __launch_bounds__(256, 4) void mfma_gemm(
    const unsigned short* __restrict__ a1h, const unsigned short* __restrict__ a1l, int sA, int KA,
    const unsigned short* __restrict__ a2h, const unsigned short* __restrict__ a2l,
    const unsigned short* __restrict__ bph, int Kp, int Kw,
    const float* __restrict__ vec,
    unsigned short* __restrict__ ch, unsigned short* __restrict__ cl,
    const float* __restrict__ lw, float* __restrict__ lout)
{
    __shared__ __align__(16) unsigned short lds[15360];
    const int BUF = 7680;

    int tid = threadIdx.x;
    int bid = blockIdx.x;
    int xcd = bid & 7, idx = bid >> 3;
    int mt = xcd*32 + (idx >> 2);
    int nt = idx & 3;
    int bm = mt * 32, bn = nt * 128;

    int W = tid >> 6, lane = tid & 63;
    int nw = W;
    int r31 = lane & 31, hh = lane >> 5;

    // B staging: all threads, both planes; A staging: threads 0..127.
    int srr = (tid >> 1) & 127, sh8 = (tid & 1) * 8;
    int spA = (tid >> 6) & 1;
    int rowA = (tid >> 1) & 31, shA = (tid & 1) * 8;
    bool doA = (tid < 128);

    const unsigned short* Arow1 = (spA ? a1l : a1h) + (size_t)(bm + rowA)*sA + shA;
    const unsigned short* Arow2 = (spA ? a2l : a2h) + (size_t)(bm + rowA)*SN1 + shA - KA;
    const unsigned short* Brow0 = bph + (size_t)(bn + srr)*Kw + sh8;
    const unsigned short* Brow1 = Brow0 + (size_t)512*Kw;

    unsigned short* wAd = lds + spA*768 + rowA*24 + shA;
    unsigned short* wBd = lds + 1536 + srr*24 + sh8;
    const unsigned short* fA = lds + r31*24 + hh*8;
    const unsigned short* fB = lds + 1536 + (nw*32 + r31)*24 + hh*8;

    int nk = Kp >> 4;

    floatx16 acc;
    for (int i = 0; i < 16; ++i) acc[i] = 0.f;

    #define GLOAD(K, AV, B0, B1) do {                                          \
        int kb_ = (K) << 4;                                                    \
        if (doA) AV = (kb_ < KA) ? *(const uint4*)(Arow1 + kb_)                \
                                 : *(const uint4*)(Arow2 + kb_);               \
        B0 = *(const uint4*)(Brow0 + kb_);                                     \
        B1 = *(const uint4*)(Brow1 + kb_);                                     \
    } while(0)

    #define STORE(BOFF, AV, B0, B1) do {                                       \
        if (doA) *(uint4*)(wAd + (BOFF)) = AV;                                 \
        *(uint4*)(wBd + (BOFF)) = B0;                                          \
        *(uint4*)(wBd + (BOFF) + 3072) = B1;                                   \
    } while(0)

    #define BARRIER() do {                                                     \
        asm volatile("s_waitcnt lgkmcnt(0)" ::: "memory");                     \
        __builtin_amdgcn_s_barrier();                                          \
    } while(0)

    #define COMPUTE(BOFF) do {                                                 \
        const unsigned short* pa = fA + (BOFF);                                \
        const unsigned short* pb = fB + (BOFF);                                \
        short8 a_h = *(const short8*)(pa);                                     \
        short8 a_l = *(const short8*)(pa + 768);                               \
        short8 b_h = *(const short8*)(pb);                                     \
        short8 b_l = *(const short8*)(pb + 3072);                              \
        acc = __builtin_amdgcn_mfma_f32_32x32x16_bf16(a_h, b_h, acc,0,0,0);    \
        acc = __builtin_amdgcn_mfma_f32_32x32x16_bf16(a_h, b_l, acc,0,0,0);    \
        acc = __builtin_amdgcn_mfma_f32_32x32x16_bf16(a_l, b_h, acc,0,0,0);    \
    } while(0)

    uint4 aA, b0A, b1A, aB, b0B, b1B;
    GLOAD(0, aA, b0A, b1A);
    if (nk > 1) GLOAD(1, aB, b0B, b1B);

    int k = 0;
    while (true) {
        STORE(0, aA, b0A, b1A);
        BARRIER();
        if (k + 2 < nk) GLOAD(k + 2, aA, b0A, b1A);
        COMPUTE(0);
        if (++k >= nk) break;
        STORE(BUF, aB, b0B, b1B);
        BARRIER();
        if (k + 2 < nk) GLOAD(k + 2, aB, b0B, b1B);
        COMPUTE(BUF);
        if (++k >= nk) break;
    }
    #undef GLOAD
    #undef STORE
    #undef BARRIER
    #undef COMPUTE

    // Epilogue: wave owns full-K 32x32 tile; no LDS use, no barrier.
    int gn = bn + nw*32 + r31;
    bool ok = gn < 400;
    float vc = ok ? vec[gn] : 0.f;
    float wv = ok ? lw[gn] : 0.f;
    #pragma unroll
    for (int j = 0; j < 16; ++j) {
        int gm = bm + (j & 3) + 8*(j >> 2) + 4*hh;
        float v = acc[j] + vc;
        v = fmaxf(v, 0.f);
        if (ch && ok) {
            unsigned short h16, l16; split2(v, h16, l16);
            ch[(size_t)gm*SH + gn] = h16;
            cl[(size_t)gm*SH + gn] = l16;
        }
        float lv = v*wv;
        #pragma unroll
        for (int o = 1; o < 32; o <<= 1) lv += __shfl_xor(lv, o);
        if (r31 == 0) atomicAdd(&lout[gm], lv);
    }
}

// ---------------- host ----------------
static inline size_t align64(size_t x) { return (x + 63) & ~(size_t)63; }

extern "C" void kernel_launch(void* const* d_in, const int* in_sizes, int n_in,
                              void* d_out, int out_size, void* d_ws, size_t ws_size,
                              hipStream_t stream)
{
    const float* raw_dense  = (const float*)d_in[0];
    const int*   raw_sparse = (const int*)d_in[1];
    const float* emb   = (const float*)d_in[2];
    const float* Pd    = (const float*)d_in[3];
    const float* Ps    = (const float*)d_in[4];
    const float* Pb    = (const float*)d_in[5];
    const float* Wc    = (const float*)d_in[6];
    const float* bc    = (const float*)d_in[7];
    const float* clf_w = (const float*)d_in[8];
    const float* clf_b = (const float*)d_in[9];
    const float* a0 = (const float*)d_in[10];
    const float* a1 = (const float*)d_in[11];
    const float* a2 = (const float*)d_in[12];
    const float* a3 = (const float*)d_in[13];
    float* out = (float*)d_out;

    char* p = (char*)d_ws;
    auto alloc = [&](size_t bytes) { char* r = p; p += align64(bytes); return r; };

    float* scal    = (float*)alloc(32*4);
    float* partial = (float*)alloc(2*EMB_BLOCKS*4);
    float* csd     = (float*)alloc(400*4);
    float* css     = (float*)alloc(400*4);
    float* csb     = (float*)alloc(400*4);
    float* cv      = (float*)alloc(4*448*4);
    float* gv      = (float*)alloc(4*448*4);
    float* scl2    = (float*)alloc(16*4);
    unsigned short* w0 = (unsigned short*)alloc((size_t)2*512*640*2);
    unsigned short* w1 = (unsigned short*)alloc((size_t)2*512*832*2);
    unsigned short* w2 = (unsigned short*)alloc((size_t)2*512*832*2);
    unsigned short* w3 = (unsigned short*)alloc((size_t)2*512*832*2);
    unsigned short* n0h = (unsigned short*)alloc((size_t)8192*SN0*2);
    unsigned short* n0l = (unsigned short*)alloc((size_t)8192*SN0*2);
    unsigned short* n1h = (unsigned short*)alloc((size_t)8192*SN1*2);
    unsigned short* n1l = (unsigned short*)alloc((size_t)8192*SN1*2);
    unsigned short* hAh = (unsigned short*)alloc((size_t)8192*SH*2);
    unsigned short* hAl = (unsigned short*)alloc((size_t)8192*SH*2);
    unsigned short* hBh = (unsigned short*)alloc((size_t)8192*SH*2);
    unsigned short* hBl = (unsigned short*)alloc((size_t)8192*SH*2);

    prep1_kernel<<<dim3(13,3),256,0,stream>>>(Pd,Ps,Pb,a0,a1,a2,a3,scal,csd,css,csb);
    embed_kernel<<<EMB_BLOCKS,256,0,stream>>>(raw_dense, raw_sparse, emb, n0h,n0l,n1h,n1l, partial);
    prepM_kernel<<<dim3(8,7,3),256,0,stream>>>(Wc,Pb,scal,w1,w2,w3);
    prep2_kernel<<<dim3(8,13,4),256,0,stream>>>(Pd,Ps,Pb,scal,w0,w1,w2,w3);
    prepvec_kernel<<<dim3(14,4),256,0,stream>>>(scal,csd,css,csb,Wc,bc,clf_w,Pb,cv,gv,scl2);
    finalize_kernel<<<33,256,0,stream>>>(clf_b, partial, scl2, out);

    // h0 = relu([node0|node1]@w0 + cv0); logits += h0@gv0
    mfma_gemm<<<1024,256,0,stream>>>(n0h,n0l,SN0,208, n1h,n1l, w0, 624,640, cv+0,    hAh,hAl, gv+0,    out);
    // h1 = relu([h0|node1]@w1 + cv1); logits += h1@gv1
    mfma_gemm<<<1024,256,0,stream>>>(hAh,hAl,SH,400,  n1h,n1l, w1, 816,832, cv+448,  hBh,hBl, gv+448,  out);
    // h2
    mfma_gemm<<<1024,256,0,stream>>>(hBh,hBl,SH,400,  n1h,n1l, w2, 816,832, cv+896,  hAh,hAl, gv+896,  out);
    // h3: logits only, no store
    mfma_gemm<<<1024,256,0,stream>>>(hAh,hAl,SH,400,  n1h,n1l, w3, 816,832, cv+1344, nullptr,nullptr, gv+1344, out);
}

// Round 7
// 397.861 us; speedup vs baseline: 1.3002x; 1.3002x over previous
//
#include <hip/hip_runtime.h>
#include <cstddef>

// DynamicNetwork via split-bf16 MFMA (hi/lo, 3 MFMA per product).
// R8: algebraic fusion — nodes 2..5 never materialized.
// R9: prepvec re-parallelized. R10/R11/R14 (reverted): schedule surgery on the
//     GEMM (async LDS, kw remap, raw barrier, 4 blocks/CU) never beat ~1us/K-step.
// R12/R13: BM64xBN128 grid-512, 4 waves full-K — the verified 413us baseline.
// R15: shrink the work instead. P1 = node1 @ Ps computed ONCE (K=416, fp32 out);
//     every h-GEMM drops its Ps half (K 816->400, GEMM0 624->208) and adds
//     s_i*P1[m][n] in the epilogue. K-sum 3072 -> 1824 (1.7x fewer steps).
//     w0 = s1*Pd [K=208]; w_i = M_i only [K=400]; ws = split(Ps) [K=416].

typedef short short8 __attribute__((ext_vector_type(8)));
typedef float floatx16 __attribute__((ext_vector_type(16)));

#define EMB_BLOCKS 832
#define SN0 224   // node0 k-stride (208 used)
#define SN1 448   // node1 k-stride (416 used)
#define SH  416   // hidden k-stride (400 used)

__device__ __forceinline__ unsigned short f2bf(float f) {
    unsigned int u = __float_as_uint(f);
    u += 0x7fffu + ((u >> 16) & 1u);
    return (unsigned short)(u >> 16);
}
__device__ __forceinline__ float bf2f(unsigned short h) {
    return __uint_as_float((unsigned int)h << 16);
}
__device__ __forceinline__ void split2(float v, unsigned short& h, unsigned short& l) {
    h = f2bf(v);
    l = f2bf(v - bf2f(h));
}

// ---------------- prep1: column sums (39 blocks) + alpha scalars ----------------
__global__ __launch_bounds__(256) void prep1_kernel(
    const float* __restrict__ Pd, const float* __restrict__ Ps, const float* __restrict__ Pb,
    const float* __restrict__ a0, const float* __restrict__ a1,
    const float* __restrict__ a2, const float* __restrict__ a3,
    float* __restrict__ scal,
    float* __restrict__ csd, float* __restrict__ css, float* __restrict__ csb)
{
    int t = threadIdx.x;
    int y = blockIdx.y;
    int c = t & 31, rg = t >> 5;
    int col = blockIdx.x * 32 + c;
    const float* src = (y==0) ? Pd : (y==1) ? Ps : Pb;
    int K = (y==0) ? 208 : (y==1) ? 416 : 400;
    float* out = (y==0) ? csd : (y==1) ? css : csb;
    float s = 0.f;
    if (col < 400)
        for (int k = rg; k < K; k += 8) s += src[(size_t)k*400 + col];
    __shared__ float red[8][32];
    red[rg][c] = s;
    __syncthreads();
    if (rg == 0 && col < 400) {
        float tot = 0.f;
        #pragma unroll
        for (int r = 0; r < 8; ++r) tot += red[r][c];
        out[col] = tot;
    }
    if (blockIdx.x == 0 && y == 0 && t < 4) {
        int i = t;
        const float* a = (i==0) ? a0 : (i==1) ? a1 : (i==2) ? a2 : a3;
        int np = 2 + i;
        float sum1 = 0.f, sum2 = 0.f, sumc = 0.f;
        for (int j = 0; j < np; ++j) { sum1 += a[j]; sum2 += a[np+j]; }
        for (int j = 0; j < 4; ++j) sumc += a[2*np+j];
        int i1 = (i==0) ? 0 : 1;
        int i2 = i + 1;
        int kk = i;
        float s1 = a[i1],      c1 = sum1 - s1;
        float s2 = a[np+i2],   c2 = sum2 - s2;
        float sk = a[2*np+kk], ck = sumc - sk;
        float* sl = scal + i*8;
        if (i == 0) { sl[0]=s1; sl[1]=c1; sl[2]=s2; sl[3]=c2; }
        else        { sl[0]=s2; sl[1]=c2; sl[2]=s1; sl[3]=c1; }
        sl[4] = sk; sl[5] = ck;
    }
}

// ---------------- prep2: w0 = s1*Pd (K=208) ; ws = Ps unscaled (K=416) ----------------
// Split bf16 hi/lo planes [2][512][Kw], transposed to [n][k].
__global__ __launch_bounds__(256) void prep2_kernel(
    const float* __restrict__ Pd, const float* __restrict__ Ps,
    const float* __restrict__ scal,
    unsigned short* __restrict__ w0, unsigned short* __restrict__ ws)
{
    int z = blockIdx.z;
    int Kp = (z==0) ? 208 : 416;
    int Kw = Kp;
    const float* src = (z==0) ? Pd : Ps;
    unsigned short* dst = (z==0) ? w0 : ws;

    int ktiles = (Kp + 63) >> 6;
    if ((int)blockIdx.y >= ktiles) return;
    float sc = (z==0) ? scal[0] : 1.f;
    int k0 = blockIdx.y * 64, n0 = blockIdx.x * 64;
    __shared__ float T[64][65];
    int t = threadIdx.x;
    {
        int kr = t >> 2, c0 = (t & 3) * 16;
        int gk = k0 + kr;
        bool kok = gk < Kp;
        for (int j = 0; j < 16; j += 4) {
            int n = n0 + c0 + j;
            float4 v = make_float4(0.f,0.f,0.f,0.f);
            if (kok && n < 400) v = *(const float4*)&src[(size_t)gk*400 + n];
            T[kr][c0+j+0] = v.x * sc;
            T[kr][c0+j+1] = v.y * sc;
            T[kr][c0+j+2] = v.z * sc;
            T[kr][c0+j+3] = v.w * sc;
        }
    }
    __syncthreads();
    {
        int nr = t >> 2, kc0 = (t & 3) * 16;
        int gn = n0 + nr;
        int gk0 = k0 + kc0;
        if (gk0 >= Kp) return;
        unsigned short hb[16], lb[16];
        for (int j = 0; j < 16; ++j) {
            float v = (gn < 400) ? T[kc0+j][nr] : 0.f;
            split2(v, hb[j], lb[j]);
        }
        unsigned short* dh = dst + (size_t)gn*Kw + gk0;
        unsigned short* dl = dst + (size_t)512*Kw + (size_t)gn*Kw + gk0;
        *(uint4*)&dh[0] = *(uint4*)&hb[0]; *(uint4*)&dh[8] = *(uint4*)&hb[8];
        *(uint4*)&dl[0] = *(uint4*)&lb[0]; *(uint4*)&dl[8] = *(uint4*)&lb[8];
    }
}

// ---------------- prepM: M_g = s2_g * sk_{g-1} * (Wc_{g-1} @ Pb), g = z+1 ----------------
// fp32 64x64-tile GEMM; writes transposed+split into w_g planes [n][k], Kw=400.
__global__ __launch_bounds__(256) void prepM_kernel(
    const float* __restrict__ Wc, const float* __restrict__ Pb,
    const float* __restrict__ scal,
    unsigned short* __restrict__ w1, unsigned short* __restrict__ w2,
    unsigned short* __restrict__ w3)
{
    int z = blockIdx.z;                   // 0..2 -> GEMM g = z+1
    unsigned short* dst = (z==0) ? w1 : (z==1) ? w2 : w3;
    const float* A = Wc + (size_t)z*5*160000;   // Wc[z, kk=z] : [400k][400j]
    float scale = scal[(z+1)*8+0] * scal[z*8+4];
    const int Kw = 400;

    __shared__ float As[16][68];   // [j][k]
    __shared__ float Ws[16][68];   // [j][n]
    int t = threadIdx.x;
    int tx = t & 15, ty = t >> 4;
    int bk = blockIdx.y * 64;
    int bn = blockIdx.x * 64;
    int arow = t >> 2;
    int aj4  = (t & 3) << 2;
    int wrow = t >> 4;
    int wc4  = (t & 15) << 2;
    float acc[4][4] = {};
    for (int j0 = 0; j0 < 400; j0 += 16) {
        float4 av = make_float4(0.f,0.f,0.f,0.f);
        if (bk + arow < 400) av = *(const float4*)&A[(size_t)(bk+arow)*400 + j0 + aj4];
        float4 wv = make_float4(0.f,0.f,0.f,0.f);
        if (bn + wc4 < 400) wv = *(const float4*)&Pb[(size_t)(j0+wrow)*400 + bn + wc4];
        __syncthreads();
        As[aj4+0][arow] = av.x;
        As[aj4+1][arow] = av.y;
        As[aj4+2][arow] = av.z;
        As[aj4+3][arow] = av.w;
        *(float4*)&Ws[wrow][wc4] = wv;
        __syncthreads();
        #pragma unroll
        for (int jj = 0; jj < 16; ++jj) {
            float4 a4 = *(const float4*)&As[jj][ty<<2];
            float4 b4 = *(const float4*)&Ws[jj][tx<<2];
            acc[0][0] += a4.x*b4.x; acc[0][1] += a4.x*b4.y; acc[0][2] += a4.x*b4.z; acc[0][3] += a4.x*b4.w;
            acc[1][0] += a4.y*b4.x; acc[1][1] += a4.y*b4.y; acc[1][2] += a4.y*b4.z; acc[1][3] += a4.y*b4.w;
            acc[2][0] += a4.z*b4.x; acc[2][1] += a4.z*b4.y; acc[2][2] += a4.z*b4.z; acc[2][3] += a4.z*b4.w;
            acc[3][0] += a4.w*b4.x; acc[3][1] += a4.w*b4.y; acc[3][2] += a4.w*b4.z; acc[3][3] += a4.w*b4.w;
        }
    }
    int gk0 = bk + (ty << 2);
    int gn0 = bn + (tx << 2);
    #pragma unroll
    for (int ik = 0; ik < 4; ++ik) {
        int gk = gk0 + ik;
        if (gk >= 400) break;
        #pragma unroll
        for (int in = 0; in < 4; ++in) {
            int gn = gn0 + in;
            float v = (gn < 400) ? acc[ik][in] * scale : 0.f;
            unsigned short h16, l16; split2(v, h16, l16);
            dst[(size_t)gn*Kw + gk] = h16;
            dst[(size_t)512*Kw + (size_t)gn*Kw + gk] = l16;
        }
    }
}

// ---------------- prepvec: C_i, gv_i, scalar consts (56 blocks) ----------------
__global__ __launch_bounds__(256) void prepvec_kernel(
    const float* __restrict__ scal,
    const float* __restrict__ csd, const float* __restrict__ css, const float* __restrict__ csb,
    const float* __restrict__ Wc, const float* __restrict__ bc,
    const float* __restrict__ clf_w, const float* __restrict__ Pb,
    float* __restrict__ cv, float* __restrict__ gv, float* __restrict__ scl2)
{
    int i = blockIdx.y;
    int tid = threadIdx.x;
    int tbase = blockIdx.x * 32;
    const float* cw = clf_w + i*400;
    float ski = scal[i*8+4], cki = scal[i*8+5];
    const float* A = Wc + (size_t)i*5*160000;

    int wv = tid >> 6, lane = tid & 63;
    #pragma unroll
    for (int q = 0; q < 8; ++q) {
        int t = tbase + wv*8 + q;
        float s = 0.f;
        if (t < 400) {
            const float* wr = A + (size_t)t*400;
            for (int j = lane; j < 400; j += 64) s += wr[j]*cw[j];
            #pragma unroll
            for (int o = 32; o > 0; o >>= 1) s += __shfl_xor(s, o);
        }
        if (lane == 0) gv[i*448 + t] = (t < 400) ? ski * s : 0.f;
    }

    __shared__ float bpred[8][32];
    int t = tbase + (tid & 31);
    int jc = tid >> 5;
    float bp_part = 0.f;
    if (i > 0 && t < 400) {
        const float* bcp = bc + (size_t)(i-1)*5*400;
        for (int j = jc*50; j < jc*50 + 50; ++j)
            bp_part += bcp[j] * Pb[(size_t)j*400 + t];
    }
    bpred[jc][tid & 31] = bp_part;
    __syncthreads();
    if (tid < 32) {
        float bp = 0.f;
        #pragma unroll
        for (int r = 0; r < 8; ++r) bp += bpred[r][tid];
        float c = 0.f;
        if (t < 400) {
            if (i == 0) {
                c = scal[1]*csd[t] + scal[3]*css[t];
            } else {
                float s2 = scal[i*8+0], c2 = scal[i*8+1];
                float c1 = scal[i*8+3];
                float skp = scal[(i-1)*8+4], ckp = scal[(i-1)*8+5];
                c = c1*css[t] + (c2 + s2*ckp)*csb[t] + s2*skp*bp;
            }
        }
        cv[i*448 + t] = c;
    }

    if (blockIdx.x == 0) {
        const float* bci = bc + (size_t)i*5*400;
        float sc = 0.f;
        for (int j = tid; j < 400; j += 256) sc += (ski*bci[j] + cki)*cw[j];
        #pragma unroll
        for (int o = 32; o > 0; o >>= 1) sc += __shfl_down(sc, o);
        __shared__ float red[4];
        int wv2 = tid >> 6, ln = tid & 63;
        if (ln == 0) red[wv2] = sc;
        __syncthreads();
        if (tid == 0) scl2[i] = red[0]+red[1]+red[2]+red[3];
    }
}

// ---------------- embed: node0/node1 bf16 hi/lo planes (padded strides) ----------------
__global__ __launch_bounds__(256) void embed_kernel(
    const float* __restrict__ rd, const int* __restrict__ rs,
    const float* __restrict__ emb,
    unsigned short* __restrict__ n0h, unsigned short* __restrict__ n0l,
    unsigned short* __restrict__ n1h, unsigned short* __restrict__ n1l,
    float* __restrict__ partial)
{
    int tid0 = blockIdx.x*256 + threadIdx.x;
    int nth = gridDim.x*256;
    float ssq = 0.f, dsq = 0.f;
    for (int it = tid0; it < 8192*26; it += nth) {
        int b = it / 26, s = it - b*26;
        int row = 13 + 50000*s + rs[b*26 + s];
        const float* e = emb + (size_t)row*16;
        float4 e0 = *(const float4*)&e[0], e1 = *(const float4*)&e[4];
        float4 e2 = *(const float4*)&e[8], e3 = *(const float4*)&e[12];
        float vv[16] = {e0.x,e0.y,e0.z,e0.w, e1.x,e1.y,e1.z,e1.w,
                        e2.x,e2.y,e2.z,e2.w, e3.x,e3.y,e3.z,e3.w};
        unsigned short hb[16], lb[16];
        for (int j = 0; j < 16; ++j) { ssq += vv[j]*vv[j]; split2(vv[j], hb[j], lb[j]); }
        size_t off = (size_t)b*SN1 + s*16;
        *(uint4*)&n1h[off] = *(uint4*)&hb[0]; *(uint4*)&n1h[off+8] = *(uint4*)&hb[8];
        *(uint4*)&n1l[off] = *(uint4*)&lb[0]; *(uint4*)&n1l[off+8] = *(uint4*)&lb[8];
    }
    for (int it = tid0; it < 8192*13; it += nth) {
        int b = it / 13, f = it - b*13;
        float sc = rd[b*13 + f];
        const float* e = emb + (size_t)f*16;
        float4 e0 = *(const float4*)&e[0], e1 = *(const float4*)&e[4];
        float4 e2 = *(const float4*)&e[8], e3 = *(const float4*)&e[12];
        float vv[16] = {e0.x,e0.y,e0.z,e0.w, e1.x,e1.y,e1.z,e1.w,
                        e2.x,e2.y,e2.z,e2.w, e3.x,e3.y,e3.z,e3.w};
        unsigned short hb[16], lb[16];
        for (int j = 0; j < 16; ++j) { float v = vv[j]*sc; dsq += v*v; split2(v, hb[j], lb[j]); }
        size_t off = (size_t)b*SN0 + f*16;
        *(uint4*)&n0h[off] = *(uint4*)&hb[0]; *(uint4*)&n0h[off+8] = *(uint4*)&hb[8];
        *(uint4*)&n0l[off] = *(uint4*)&lb[0]; *(uint4*)&n0l[off+8] = *(uint4*)&lb[8];
    }
    for (int o = 32; o > 0; o >>= 1) { ssq += __shfl_down(ssq, o); dsq += __shfl_down(dsq, o); }
    __shared__ float red[8];
    int wave = threadIdx.x >> 6, lane = threadIdx.x & 63;
    if (lane == 0) { red[wave] = dsq; red[4+wave] = ssq; }
    __syncthreads();
    if (threadIdx.x == 0) {
        partial[blockIdx.x*2]   = red[0]+red[1]+red[2]+red[3];
        partial[blockIdx.x*2+1] = red[4]+red[5]+red[6]+red[7];
    }
}

// blocks 0..31: out[b] = clf_b + sum_i scl2[i]; block 32: regs
__global__ __launch_bounds__(256) void finalize_kernel(
    const float* __restrict__ clf_b, const float* __restrict__ partial,
    const float* __restrict__ scl2, float* __restrict__ out)
{
    if (blockIdx.x < 32) {
        float base = clf_b[0] + scl2[0] + scl2[1] + scl2[2] + scl2[3];
        out[blockIdx.x*256 + threadIdx.x] = base;
        return;
    }
    float d = 0.f, s = 0.f;
    for (int i = threadIdx.x; i < EMB_BLOCKS; i += 256) { d += partial[2*i]; s += partial[2*i+1]; }
    for (int o = 32; o > 0; o >>= 1) { d += __shfl_down(d, o); s += __shfl_down(s, o); }
    __shared__ float red[8];
    int wave = threadIdx.x >> 6, lane = threadIdx.x & 63;
    if (lane == 0) { red[wave] = d; red[4+wave] = s; }
    __syncthreads();
    if (threadIdx.x == 0) {
        float dd = red[0]+red[1]+red[2]+red[3];
        float ss = red[4]+red[5]+red[6]+red[7];
        out[8192] = 1e-5f * (sqrtf(dd) + sqrtf(ss));
    }
}

// ---------------- R15 MFMA GEMM: BM64 x BN128, 4 waves, full-K (R13 structure) ----------------
// Modes: p1out!=nullptr -> raw fp32 store (P1 pass), no relu/logits/ch.
//        fadd!=nullptr  -> epilogue v += (*fsp) * fadd[gm*400+gn] before relu.
__global__ __launch_bounds__(256, 4) void mfma_gemm(
    const unsigned short* __restrict__ a1h, const unsigned short* __restrict__ a1l, int sA,
    const unsigned short* __restrict__ bph, int Kp, int Kw,
    const float* __restrict__ vec,
    unsigned short* __restrict__ ch, unsigned short* __restrict__ cl,
    const float* __restrict__ lw, float* __restrict__ lout,
    float* __restrict__ p1out, const float* __restrict__ fadd, const float* __restrict__ fsp)
{
    __shared__ __align__(16) unsigned short lds[18432];

    int tid = threadIdx.x;
    int bid = blockIdx.x;
    int xcd = bid & 7, idx = bid >> 3;
    int mt = xcd*16 + (idx >> 2);
    int nt = idx & 3;
    int bm = mt * 64, bn = nt * 128;

    int W = tid >> 6, lane = tid & 63;
    int mw = W & 1, nw = W >> 1;
    int r31 = lane & 31, hh = lane >> 5;

    // staging roles: A chunk (2pl x 64row x 2half = 256 chunks = 256 threads)
    int spA = tid >> 7, uA = tid & 127;
    int rowA = uA >> 1, shA = (uA & 1) * 8;
    int srr = (tid >> 1) & 127, sh8 = (tid & 1) * 8;

    const unsigned short* Arow = (spA ? a1l : a1h) + (size_t)(bm + rowA)*sA + shA;
    const unsigned short* Brow0 = bph + (size_t)(bn + srr)*Kw + sh8;
    const unsigned short* Brow1 = Brow0 + (size_t)512*Kw;

    unsigned short* wAd = lds + spA*1536 + rowA*24 + shA;
    unsigned short* wBd = lds + 6144 + srr*24 + sh8;
    const unsigned short* fA = lds + (mw*32 + r31)*24 + hh*8;
    const unsigned short* fB = lds + 6144 + (nw*64 + r31)*24 + hh*8;

    int nk = Kp >> 4;

    floatx16 acc0, acc1;
    for (int i = 0; i < 16; ++i) { acc0[i] = 0.f; acc1[i] = 0.f; }

    #define GLOAD(K, AV, B0, B1) do {                                          \
        int kb_ = (K) << 4;                                                    \
        AV = *(const uint4*)(Arow + kb_);                                      \
        B0 = *(const uint4*)(Brow0 + kb_);                                     \
        B1 = *(const uint4*)(Brow1 + kb_);                                     \
    } while(0)

    #define COMPUTE(BA, BB) do {                                               \
        const unsigned short* pa = fA + (BA);                                  \
        const unsigned short* pb = fB + (BB);                                  \
        short8 a_h = *(const short8*)(pa);                                     \
        short8 a_l = *(const short8*)(pa + 1536);                              \
        short8 b0h = *(const short8*)(pb);                                     \
        short8 b1h = *(const short8*)(pb + 768);                               \
        short8 b0l = *(const short8*)(pb + 3072);                              \
        short8 b1l = *(const short8*)(pb + 3840);                              \
        acc0 = __builtin_amdgcn_mfma_f32_32x32x16_bf16(a_h, b0h, acc0,0,0,0);  \
        acc1 = __builtin_amdgcn_mfma_f32_32x32x16_bf16(a_h, b1h, acc1,0,0,0);  \
        acc0 = __builtin_amdgcn_mfma_f32_32x32x16_bf16(a_h, b0l, acc0,0,0,0);  \
        acc1 = __builtin_amdgcn_mfma_f32_32x32x16_bf16(a_h, b1l, acc1,0,0,0);  \
        acc0 = __builtin_amdgcn_mfma_f32_32x32x16_bf16(a_l, b0h, acc0,0,0,0);  \
        acc1 = __builtin_amdgcn_mfma_f32_32x32x16_bf16(a_l, b1h, acc1,0,0,0);  \
    } while(0)

    uint4 avA, b0A, b1A, avB, b0B, b1B;
    GLOAD(0, avA, b0A, b1A);
    if (nk > 1) GLOAD(1, avB, b0B, b1B);

    int k = 0;
    while (true) {
        *(uint4*)(wAd) = avA;
        *(uint4*)(wBd) = b0A;
        *(uint4*)(wBd + 3072) = b1A;
        __syncthreads();
        if (k + 2 < nk) GLOAD(k + 2, avA, b0A, b1A);
        COMPUTE(0, 0);
        if (++k >= nk) break;
        *(uint4*)(wAd + 3072) = avB;
        *(uint4*)(wBd + 6144) = b0B;
        *(uint4*)(wBd + 6144 + 3072) = b1B;
        __syncthreads();
        if (k + 2 < nk) GLOAD(k + 2, avB, b0B, b1B);
        COMPUTE(3072, 6144);
        if (++k >= nk) break;
    }
    #undef GLOAD
    #undef COMPUTE

    // Epilogue: each wave owns its full-K 32x64 quadrant pair.
    int gn0 = bn + nw*64 + r31;
    int gn1 = gn0 + 32;
    bool ok0 = gn0 < 400, ok1 = gn1 < 400;

    if (p1out) {
        #pragma unroll
        for (int j = 0; j < 16; ++j) {
            int gm = bm + mw*32 + (j & 3) + 8*(j >> 2) + 4*hh;
            if (ok0) p1out[(size_t)gm*400 + gn0] = acc0[j];
            if (ok1) p1out[(size_t)gm*400 + gn1] = acc1[j];
        }
        return;
    }

    float vc0 = ok0 ? vec[gn0] : 0.f;
    float vc1 = ok1 ? vec[gn1] : 0.f;
    float wv0 = ok0 ? lw[gn0] : 0.f;
    float wv1 = ok1 ? lw[gn1] : 0.f;
    float fs = fadd ? *fsp : 0.f;
    #pragma unroll
    for (int j = 0; j < 16; ++j) {
        int gm = bm + mw*32 + (j & 3) + 8*(j >> 2) + 4*hh;
        float v0 = acc0[j] + vc0;
        float v1 = acc1[j] + vc1;
        if (fadd) {
            if (ok0) v0 += fs * fadd[(size_t)gm*400 + gn0];
            if (ok1) v1 += fs * fadd[(size_t)gm*400 + gn1];
        }
        v0 = fmaxf(v0, 0.f); v1 = fmaxf(v1, 0.f);
        if (ch) {
            if (ok0) {
                unsigned short h16, l16; split2(v0, h16, l16);
                ch[(size_t)gm*SH + gn0] = h16;
                cl[(size_t)gm*SH + gn0] = l16;
            }
            if (ok1) {
                unsigned short h16, l16; split2(v1, h16, l16);
                ch[(size_t)gm*SH + gn1] = h16;
                cl[(size_t)gm*SH + gn1] = l16;
            }
        }
        float lv = v0*wv0 + v1*wv1;
        #pragma unroll
        for (int o = 1; o < 32; o <<= 1) lv += __shfl_xor(lv, o);
        if (r31 == 0) atomicAdd(&lout[gm], lv);
    }
}

// ---------------- host ----------------
static inline size_t align64(size_t x) { return (x + 63) & ~(size_t)63; }

extern "C" void kernel_launch(void* const* d_in, const int* in_sizes, int n_in,
                              void* d_out, int out_size, void* d_ws, size_t ws_size,
                              hipStream_t stream)
{
    const float* raw_dense  = (const float*)d_in[0];
    const int*   raw_sparse = (const int*)d_in[1];
    const float* emb   = (const float*)d_in[2];
    const float* Pd    = (const float*)d_in[3];
    const float* Ps    = (const float*)d_in[4];
    const float* Pb    = (const float*)d_in[5];
    const float* Wc    = (const float*)d_in[6];
    const float* bc    = (const float*)d_in[7];
    const float* clf_w = (const float*)d_in[8];
    const float* clf_b = (const float*)d_in[9];
    const float* a0 = (const float*)d_in[10];
    const float* a1 = (const float*)d_in[11];
    const float* a2 = (const float*)d_in[12];
    const float* a3 = (const float*)d_in[13];
    float* out = (float*)d_out;

    char* p = (char*)d_ws;
    auto alloc = [&](size_t bytes) { char* r = p; p += align64(bytes); return r; };

    float* scal    = (float*)alloc(32*4);
    float* partial = (float*)alloc(2*EMB_BLOCKS*4);
    float* csd     = (float*)alloc(400*4);
    float* css     = (float*)alloc(400*4);
    float* csb     = (float*)alloc(400*4);
    float* cv      = (float*)alloc(4*448*4);
    float* gv      = (float*)alloc(4*448*4);
    float* scl2    = (float*)alloc(16*4);
    unsigned short* w0 = (unsigned short*)alloc((size_t)2*512*208*2);
    unsigned short* w1 = (unsigned short*)alloc((size_t)2*512*400*2);
    unsigned short* w2 = (unsigned short*)alloc((size_t)2*512*400*2);
    unsigned short* w3 = (unsigned short*)alloc((size_t)2*512*400*2);
    unsigned short* ws = (unsigned short*)alloc((size_t)2*512*416*2);
    float* p1 = (float*)alloc((size_t)8192*400*4);
    unsigned short* n0h = (unsigned short*)alloc((size_t)8192*SN0*2);
    unsigned short* n0l = (unsigned short*)alloc((size_t)8192*SN0*2);
    unsigned short* n1h = (unsigned short*)alloc((size_t)8192*SN1*2);
    unsigned short* n1l = (unsigned short*)alloc((size_t)8192*SN1*2);
    unsigned short* hAh = (unsigned short*)alloc((size_t)8192*SH*2);
    unsigned short* hAl = (unsigned short*)alloc((size_t)8192*SH*2);
    unsigned short* hBh = (unsigned short*)alloc((size_t)8192*SH*2);
    unsigned short* hBl = (unsigned short*)alloc((size_t)8192*SH*2);

    prep1_kernel<<<dim3(13,3),256,0,stream>>>(Pd,Ps,Pb,a0,a1,a2,a3,scal,csd,css,csb);
    embed_kernel<<<EMB_BLOCKS,256,0,stream>>>(raw_dense, raw_sparse, emb, n0h,n0l,n1h,n1l, partial);
    prepM_kernel<<<dim3(8,7,3),256,0,stream>>>(Wc,Pb,scal,w1,w2,w3);
    prep2_kernel<<<dim3(8,7,2),256,0,stream>>>(Pd,Ps,scal,w0,ws);
    prepvec_kernel<<<dim3(14,4),256,0,stream>>>(scal,csd,css,csb,Wc,bc,clf_w,Pb,cv,gv,scl2);
    finalize_kernel<<<33,256,0,stream>>>(clf_b, partial, scl2, out);

    // P1 = node1 @ Ps  (fp32, computed once, reused by all 4 h-GEMMs)
    mfma_gemm<<<512,256,0,stream>>>(n1h,n1l,SN1, ws, 416,416, nullptr, nullptr,nullptr,
                                    nullptr, nullptr, p1, nullptr, nullptr);
    // h0 = relu(node0@(s1 Pd) + s2*P1 + cv0); logits += h0@gv0
    mfma_gemm<<<512,256,0,stream>>>(n0h,n0l,SN0, w0, 208,208, cv+0,    hAh,hAl, gv+0,    out,
                                    nullptr, p1, scal+2);
    // h1 = relu(h0@M1 + s1_1*P1 + cv1); logits += h1@gv1
    mfma_gemm<<<512,256,0,stream>>>(hAh,hAl,SH,  w1, 400,400, cv+448,  hBh,hBl, gv+448,  out,
                                    nullptr, p1, scal+8+2);
    // h2
    mfma_gemm<<<512,256,0,stream>>>(hBh,hBl,SH,  w2, 400,400, cv+896,  hAh,hAl, gv+896,  out,
                                    nullptr, p1, scal+16+2);
    // h3: logits only, no store
    mfma_gemm<<<512,256,0,stream>>>(hAh,hAl,SH,  w3, 400,400, cv+1344, nullptr,nullptr, gv+1344, out,
                                    nullptr, p1, scal+24+2);
}